// Round 8
// baseline (474.859 us; speedup 1.0000x reference)
//
#include <hip/hip_runtime.h>
#include <stdint.h>
#include <stddef.h>

#define N_NODES 8192
#define N_FEAT  512
#define EMB     128
#define N_HEADS 4
#define BT      64                      // block tile
#define TG      (N_NODES / BT)          // 128
#define NPAIR   (TG * (TG + 1) / 2)     // 8256 (divisible by 8)

typedef __attribute__((ext_vector_type(8)))  short bf16x8;
typedef __attribute__((ext_vector_type(16))) float f32x16;

__device__ __forceinline__ unsigned short f2bf(float f) {
  union { float f; unsigned int u; } x; x.f = f;
  unsigned int r = (x.u + 0x7FFFu + ((x.u >> 16) & 1u)) >> 16;
  return (unsigned short)r;
}
__device__ __forceinline__ float bf2f(unsigned short u) {
  union { unsigned int u; float f; } x; x.u = ((unsigned int)u) << 16;
  return x.f;
}

// fragment-linear flat index (shorts): 32-row groups g = n>>5,
// layout [g][kk=k>>4][lane=((k>>3)&1)<<5 | (n&31)][e=k&7]; group base = g<<12.
__device__ __forceinline__ size_t frag_flat(int n, int k) {
  return ((size_t)(((n >> 6) * 2 + ((n >> 5) & 1)) * 8 + (k >> 4)) * 64
          + ((((k >> 3) & 1) << 5) | (n & 31))) * 8 + (k & 7);
}

// bf16 [64][64] transpose buffer; <=2 lanes/bank in natural AND transposed use
__device__ __forceinline__ int tidx64(int r, int c) {
  return r * 64 + (c ^ (r & 31));
}

// ---------- kernel 1: X_emb = X@W, row-normalize, bf16, fragment-linear write ----------
__global__ void __launch_bounds__(512) xw_kernel(const float* __restrict__ X,
                                                 const float* __restrict__ W,
                                                 unsigned short* __restrict__ Xf) {
  __shared__ float xs[32][N_FEAT];    // 64KB
  const int t = threadIdx.x;
  const int row0 = blockIdx.x * 32;
#pragma unroll
  for (int i = 0; i < 8; ++i) {
    int e4 = i * 512 + t;
    int row = e4 >> 7;
    int col = (e4 & 127) * 4;
    *(float4*)&xs[row][col] = *(const float4*)&X[(size_t)(row0 + row) * N_FEAT + col];
  }
  __syncthreads();
  const int c0 = (t & 31) * 4;
  const int r0 = (t >> 5) * 2;
  float a00=0.f,a01=0.f,a02=0.f,a03=0.f,a10=0.f,a11=0.f,a12=0.f,a13=0.f;
  for (int k = 0; k < N_FEAT; k += 2) {
    float4 w0 = *(const float4*)&W[(size_t)k * EMB + c0];
    float4 w1 = *(const float4*)&W[(size_t)(k + 1) * EMB + c0];
    float x00 = xs[r0][k],     x01 = xs[r0][k + 1];
    float x10 = xs[r0 + 1][k], x11 = xs[r0 + 1][k + 1];
    a00 += x00*w0.x; a01 += x00*w0.y; a02 += x00*w0.z; a03 += x00*w0.w;
    a10 += x10*w0.x; a11 += x10*w0.y; a12 += x10*w0.z; a13 += x10*w0.w;
    a00 += x01*w1.x; a01 += x01*w1.y; a02 += x01*w1.z; a03 += x01*w1.w;
    a10 += x11*w1.x; a11 += x11*w1.y; a12 += x11*w1.z; a13 += x11*w1.w;
  }
  float s0 = a00*a00 + a01*a01 + a02*a02 + a03*a03;
  float s1 = a10*a10 + a11*a11 + a12*a12 + a13*a13;
#pragma unroll
  for (int off = 16; off >= 1; off >>= 1) {
    s0 += __shfl_xor(s0, off);
    s1 += __shfl_xor(s1, off);
  }
  float inv0 = 1.0f / (sqrtf(s0) + 1e-6f);
  float inv1 = 1.0f / (sqrtf(s1) + 1e-6f);
  union { unsigned short u[4]; uint2 v; } o0, o1;
  o0.u[0]=f2bf(a00*inv0); o0.u[1]=f2bf(a01*inv0); o0.u[2]=f2bf(a02*inv0); o0.u[3]=f2bf(a03*inv0);
  o1.u[0]=f2bf(a10*inv1); o1.u[1]=f2bf(a11*inv1); o1.u[2]=f2bf(a12*inv1); o1.u[3]=f2bf(a13*inv1);
  int n0 = row0 + r0;
  *(uint2*)&Xf[frag_flat(n0, c0)] = o0.v;
  *(uint2*)&Xf[frag_flat(n0 + 1, c0)] = o1.v;
}

// ---------- kernel 2: Z row-normalize + bf16, fragment-linear write ----------
__global__ void __launch_bounds__(256) znorm_kernel(const float* __restrict__ in,
                                                    unsigned short* __restrict__ Zf) {
  const int row = blockIdx.x * 4 + (threadIdx.x >> 6);
  const int lane = threadIdx.x & 63;
  float2 v = *(const float2*)&in[(size_t)row * EMB + lane * 2];
  float ss = v.x * v.x + v.y * v.y;
#pragma unroll
  for (int off = 32; off >= 1; off >>= 1) ss += __shfl_xor(ss, off);
  const float s = 1.0f / (sqrtf(ss) + 1e-6f);
  union { unsigned short u[2]; unsigned int w; } o;
  o.u[0] = f2bf(v.x * s);
  o.u[1] = f2bf(v.y * s);
  const int h = row >> 13;
  const int n = row & 8191;
  const int c = lane * 2;
  size_t flat = ((size_t)h << 20) + frag_flat(n, c);
  *(unsigned int*)&Zf[flat] = o.w;
}

// ---------- kernel 3 helpers ----------
__device__ __forceinline__ void aload(bf16x8 (&DST)[8],
                                      const unsigned short* __restrict__ base, int lo) {
#pragma unroll
  for (int kk = 0; kk < 8; ++kk) DST[kk] = *(const bf16x8*)&base[kk * 512 + lo];
}

__device__ __forceinline__ void mstep(const bf16x8 (&A)[8], const bf16x8 (&B)[8],
                                      f32x16& m) {
  f32x16 acc = {};
  __builtin_amdgcn_s_setprio(1);
#pragma unroll
  for (int kk = 0; kk < 8; ++kk)
    acc = __builtin_amdgcn_mfma_f32_32x32x16_bf16(A[kk], B[kk], acc, 0, 0, 0);
  __builtin_amdgcn_s_setprio(0);
#pragma unroll
  for (int q = 0; q < 16; ++q) m[q] = fmaxf(m[q], acc[q]);
}

// ---------- kernel 3: fused affinity — 64x64 pair-tile, operand-swap symmetrize ----------
__global__ void __launch_bounds__(256, 4)
affinity_kernel(const unsigned short* __restrict__ Xf,
                const unsigned short* __restrict__ Zf,
                const float* __restrict__ betap,
                float* __restrict__ out) {
  __shared__ unsigned short Tb[BT * BT];   // 8 KB

  // XCD-bijective swizzle (8256 % 8 == 0)
  int bid = blockIdx.x;
  int p = (bid & 7) * (NPAIR / 8) + (bid >> 3);
  // triangular decode p -> (bi <= bj)
  int i = (int)(((float)(2 * TG + 1) -
                 sqrtf((float)((2 * TG + 1) * (2 * TG + 1) - 8 * p))) * 0.5f);
  if (i < 0) i = 0;
  if (i > TG - 1) i = TG - 1;
  while (i > 0 && i * TG - i * (i - 1) / 2 > p) --i;
  while ((i + 1) * TG - (i + 1) * i / 2 <= p) ++i;
  const int bi = i;
  const int bj = i + (p - (i * TG - i * (i - 1) / 2));
  const bool diag = (bi == bj);

  const int t = threadIdx.x;
  const int lane = t & 63;
  const int wid = t >> 6;            // 4 waves: 2 row-groups x 2 col-groups
  const int rb = wid >> 1, cb = wid & 1;
  const int R0 = rb * 32, C0 = cb * 32;
  const int fr = lane & 31, fh = lane >> 5;
  const int lo = lane * 8;

  const size_t HS = (size_t)1 << 20;                 // Zf head stride (shorts)
  const size_t gIr = (size_t)(bi * 2 + rb) << 12;    // bi-tile, row-group rb
  const size_t gJc = (size_t)(bj * 2 + cb) << 12;    // bj-tile, col-group cb
  const size_t gIc = (size_t)(bi * 2 + cb) << 12;    // bi-tile, col-group cb (phase II B... held A rows use rb)

  bf16x8 H[8], Sa[8], Sb[8];      // held operand, stream double-buffer
  f32x16 m;

  // ---- phase I: maxI[r,c] = max_h Z[h][bi,R0+r] . Xe[bj,C0+c] ----
  aload(H, Xf + gJc, lo);                         // B-held: Xe_j cols
  aload(Sa, Zf + gIr, lo);                        // A-stream h0
#pragma unroll
  for (int q = 0; q < 16; ++q) m[q] = -3.0e38f;
  aload(Sb, Zf + HS + gIr, lo);      mstep(Sa, H, m);
  aload(Sa, Zf + 2 * HS + gIr, lo);  mstep(Sb, H, m);
  aload(Sb, Zf + 3 * HS + gIr, lo);  mstep(Sa, H, m);
                                     mstep(Sb, H, m);

  // park maxI in LDS (bf16, natural (r,c), thread-private slots -> no sync)
#pragma unroll
  for (int q = 0; q < 16; ++q) {
    int r = R0 + (q & 3) + 8 * (q >> 2) + 4 * fh;
    Tb[tidx64(r, C0 + fr)] = f2bf(m[q]);
  }

  // ---- phase II: maxJT[r,c] = max_h Xe[bi,R0+r] . Z[h][bj,C0+c]  (= P_ji^T) ----
  aload(H, Xf + gIr, lo);                         // A-held: Xe_i rows
  aload(Sa, Zf + gJc, lo);                        // B-stream h0
#pragma unroll
  for (int q = 0; q < 16; ++q) m[q] = -3.0e38f;
  aload(Sb, Zf + HS + gJc, lo);      mstep(H, Sa, m);
  aload(Sa, Zf + 2 * HS + gJc, lo);  mstep(H, Sb, m);
  aload(Sb, Zf + 3 * HS + gJc, lo);  mstep(H, Sa, m);
                                     mstep(H, Sb, m);

  // ---- epilogue ----
  const float beta = betap[0];
  const bool bp = (beta != 1.0f);
  float vv[16];
#pragma unroll
  for (int q = 0; q < 16; ++q) {
    int r = R0 + (q & 3) + 8 * (q >> 2) + 4 * fh;
    int c = C0 + fr;
    float a = bf2f(Tb[tidx64(r, c)]);    // maxI (own slot)
    float v = 0.25f * (a + m[q]) + 0.5f; // ((maxI + maxJT)/2 + 1)/2
    if (bp) v = powf(v, beta);
    out[(size_t)(bi * BT + r) * N_NODES + (size_t)(bj * BT + c)] = v;
    vv[q] = v;
  }

  if (!diag) {
    __syncthreads();   // all maxI readbacks done before overwriting Tb
#pragma unroll
    for (int q = 0; q < 16; ++q) {
      int r = R0 + (q & 3) + 8 * (q >> 2) + 4 * fh;
      Tb[tidx64(C0 + fr, r)] = f2bf(vv[q]);      // park v^T
    }
    __syncthreads();
#pragma unroll
    for (int it = 0; it < 16; ++it) {
      int row = it * 4 + wid;
      int col = lane;
      out[(size_t)(bj * BT + row) * N_NODES + (size_t)(bi * BT + col)] =
          bf2f(Tb[tidx64(row, col)]);
    }
  }
  (void)gIc;
}

extern "C" void kernel_launch(void* const* d_in, const int* in_sizes, int n_in,
                              void* d_out, int out_size, void* d_ws, size_t ws_size,
                              hipStream_t stream) {
  const float* X = (const float*)d_in[0];
  const float* W = (const float*)d_in[1];
  const float* Z = (const float*)d_in[2];
  const float* beta = (const float*)d_in[3];
  float* out = (float*)d_out;
  char* ws = (char*)d_ws;

  unsigned short* Xf = (unsigned short*)ws;                // 2 MiB frag-linear bf16
  unsigned short* Zf = (unsigned short*)(ws + (2u << 20)); // 8 MiB frag-linear bf16

  hipLaunchKernelGGL(xw_kernel, dim3(N_NODES / 32), dim3(512), 0, stream, X, W, Xf);
  hipLaunchKernelGGL(znorm_kernel, dim3(N_HEADS * N_NODES / 4), dim3(256), 0, stream, Z, Zf);
  hipLaunchKernelGGL(affinity_kernel, dim3(NPAIR), dim3(256), 0, stream, Xf, Zf, beta, out);
}

// Round 9
// 188.047 us; speedup vs baseline: 2.5252x; 2.5252x over previous
//
#include <hip/hip_runtime.h>
#include <stdint.h>
#include <stddef.h>

#define N_NODES 8192
#define N_FEAT  512
#define EMB     128
#define N_HEADS 4
#define BT      128                     // block tile
#define TG      (N_NODES / BT)          // 64
#define NPAIR   (TG * (TG + 1) / 2)     // 2080 (divisible by 8)

typedef __attribute__((ext_vector_type(8)))  short bf16x8;
typedef __attribute__((ext_vector_type(16))) float f32x16;

__device__ __forceinline__ unsigned short f2bf(float f) {
  union { float f; unsigned int u; } x; x.f = f;
  unsigned int r = (x.u + 0x7FFFu + ((x.u >> 16) & 1u)) >> 16;
  return (unsigned short)r;
}

// fragment-linear flat index (shorts): 32-row groups g = n>>5,
// layout [g][kk=k>>4][lane=((k>>3)&1)<<5 | (n&31)][e=k&7]; group base = g<<12.
__device__ __forceinline__ size_t frag_flat(int n, int k) {
  return ((size_t)(((n >> 6) * 2 + ((n >> 5) & 1)) * 8 + (k >> 4)) * 64
          + ((((k >> 3) & 1) << 5) | (n & 31))) * 8 + (k & 7);
}

// f32 transpose buffer [128][128]: bank = low5(c ^ (r&31)) -> conflict-free
// for natural-row access AND transposed-column access (<=2 lanes/bank).
__device__ __forceinline__ int tidx(int r, int c) {
  return r * 128 + (c ^ (r & 31));
}

// ---------- kernel 1: X_emb = X@W, row-normalize, bf16, fragment-linear write ----------
__global__ void __launch_bounds__(512) xw_kernel(const float* __restrict__ X,
                                                 const float* __restrict__ W,
                                                 unsigned short* __restrict__ Xf) {
  __shared__ float xs[32][N_FEAT];    // 64KB
  const int t = threadIdx.x;
  const int row0 = blockIdx.x * 32;
#pragma unroll
  for (int i = 0; i < 8; ++i) {
    int e4 = i * 512 + t;
    int row = e4 >> 7;
    int col = (e4 & 127) * 4;
    *(float4*)&xs[row][col] = *(const float4*)&X[(size_t)(row0 + row) * N_FEAT + col];
  }
  __syncthreads();
  const int c0 = (t & 31) * 4;
  const int r0 = (t >> 5) * 2;
  float a00=0.f,a01=0.f,a02=0.f,a03=0.f,a10=0.f,a11=0.f,a12=0.f,a13=0.f;
  for (int k = 0; k < N_FEAT; k += 2) {
    float4 w0 = *(const float4*)&W[(size_t)k * EMB + c0];
    float4 w1 = *(const float4*)&W[(size_t)(k + 1) * EMB + c0];
    float x00 = xs[r0][k],     x01 = xs[r0][k + 1];
    float x10 = xs[r0 + 1][k], x11 = xs[r0 + 1][k + 1];
    a00 += x00*w0.x; a01 += x00*w0.y; a02 += x00*w0.z; a03 += x00*w0.w;
    a10 += x10*w0.x; a11 += x10*w0.y; a12 += x10*w0.z; a13 += x10*w0.w;
    a00 += x01*w1.x; a01 += x01*w1.y; a02 += x01*w1.z; a03 += x01*w1.w;
    a10 += x11*w1.x; a11 += x11*w1.y; a12 += x11*w1.z; a13 += x11*w1.w;
  }
  float s0 = a00*a00 + a01*a01 + a02*a02 + a03*a03;
  float s1 = a10*a10 + a11*a11 + a12*a12 + a13*a13;
#pragma unroll
  for (int off = 16; off >= 1; off >>= 1) {
    s0 += __shfl_xor(s0, off);
    s1 += __shfl_xor(s1, off);
  }
  float inv0 = 1.0f / (sqrtf(s0) + 1e-6f);
  float inv1 = 1.0f / (sqrtf(s1) + 1e-6f);
  union { unsigned short u[4]; uint2 v; } o0, o1;
  o0.u[0]=f2bf(a00*inv0); o0.u[1]=f2bf(a01*inv0); o0.u[2]=f2bf(a02*inv0); o0.u[3]=f2bf(a03*inv0);
  o1.u[0]=f2bf(a10*inv1); o1.u[1]=f2bf(a11*inv1); o1.u[2]=f2bf(a12*inv1); o1.u[3]=f2bf(a13*inv1);
  int n0 = row0 + r0;
  *(uint2*)&Xf[frag_flat(n0, c0)] = o0.v;
  *(uint2*)&Xf[frag_flat(n0 + 1, c0)] = o1.v;
}

// ---------- kernel 2: Z row-normalize + bf16, fragment-linear write ----------
__global__ void __launch_bounds__(256) znorm_kernel(const float* __restrict__ in,
                                                    unsigned short* __restrict__ Zf) {
  const int row = blockIdx.x * 4 + (threadIdx.x >> 6);
  const int lane = threadIdx.x & 63;
  float2 v = *(const float2*)&in[(size_t)row * EMB + lane * 2];
  float ss = v.x * v.x + v.y * v.y;
#pragma unroll
  for (int off = 32; off >= 1; off >>= 1) ss += __shfl_xor(ss, off);
  const float s = 1.0f / (sqrtf(ss) + 1e-6f);
  union { unsigned short u[2]; unsigned int w; } o;
  o.u[0] = f2bf(v.x * s);
  o.u[1] = f2bf(v.y * s);
  const int h = row >> 13;
  const int n = row & 8191;
  const int c = lane * 2;
  size_t flat = ((size_t)h << 20) + frag_flat(n, c);
  *(unsigned int*)&Zf[flat] = o.w;
}

// ---------- kernel 3 helpers ----------
__device__ __forceinline__ void aload(bf16x8 (&DST)[8],
                                      const unsigned short* __restrict__ base, int lo) {
#pragma unroll
  for (int kk = 0; kk < 8; ++kk) DST[kk] = *(const bf16x8*)&base[kk * 512 + lo];
}

__device__ __forceinline__ void mstep(const bf16x8 (&CUR)[8],
                                      const bf16x8 (&XB0)[8], const bf16x8 (&XB1)[8],
                                      f32x16& m0, f32x16& m1) {
  f32x16 acc0 = {}, acc1 = {};
#pragma unroll
  for (int kk = 0; kk < 8; ++kk) {
    acc0 = __builtin_amdgcn_mfma_f32_32x32x16_bf16(CUR[kk], XB0[kk], acc0, 0, 0, 0);
    acc1 = __builtin_amdgcn_mfma_f32_32x32x16_bf16(CUR[kk], XB1[kk], acc1, 0, 0, 0);
  }
#pragma unroll
  for (int q = 0; q < 16; ++q) {
    m0[q] = fmaxf(m0[q], acc0[q]);
    m1[q] = fmaxf(m1[q], acc1[q]);
  }
}

// ---------- kernel 3: fused affinity — R7 body + panel-local block ordering ----------
__global__ void __launch_bounds__(512) __attribute__((amdgpu_waves_per_eu(2)))
affinity_kernel(const unsigned short* __restrict__ Xf,
                const unsigned short* __restrict__ Zf,
                const float* __restrict__ betap,
                float* __restrict__ out) {
  __shared__ float Tb[BT * BT];   // 64 KB

  // XCD-bijective swizzle (2080 % 8 == 0): each XCD gets a contiguous p-chunk
  int bid = blockIdx.x;
  int p = (bid & 7) * (NPAIR / 8) + (bid >> 3);

  // panel decode: 4x4 super-grid of 16x16 tiles over the (bi<=bj) triangle.
  // consecutive p stay inside one super-tile -> concurrent working set ~10MB.
  int bi, bj;
  {
    int rem = p, Bi = 0, Bj = 0;
    for (Bi = 0; Bi < 4; ++Bi) {
      bool done = false;
      for (Bj = Bi; Bj < 4; ++Bj) {
        int cnt = (Bi == Bj) ? 136 : 256;
        if (rem < cnt) { done = true; break; }
        rem -= cnt;
      }
      if (done) break;
    }
    int li, lj;
    if (Bi == Bj) {
      li = 0;
      while (rem >= 16 - li) { rem -= 16 - li; ++li; }
      lj = li + rem;
    } else {
      li = rem >> 4;
      lj = rem & 15;
    }
    bi = Bi * 16 + li;
    bj = Bj * 16 + lj;
  }
  const bool diag = (bi == bj);

  const int t = threadIdx.x;
  const int lane = t & 63;
  const int wid = t >> 6;            // 8 waves: 4 row-groups x 2 col-groups
  const int rb = wid >> 1;           // 0..3 (32 rows each)
  const int cb = wid & 1;            // 0..1 (64 cols each)
  const int R0 = rb * 32, C0 = cb * 64;
  const int fr = lane & 31, fh = lane >> 5;
  const int lo = lane * 8;

  const size_t HS = (size_t)1 << 20;                 // Zf head stride (shorts)
  const size_t aI = (size_t)(bi * 4 + rb) << 12;
  const size_t aJ = (size_t)(bj * 4 + rb) << 12;
  const size_t bJ = (size_t)(bj * 4 + cb * 2) << 12;
  const size_t bI = (size_t)(bi * 4 + cb * 2) << 12;

  bf16x8 XB0[8], XB1[8], Aa[8], Ab[8];
  f32x16 m0, m1;

  // ---- phase I: m = max_h Z[h][bi-rows] . Xe[bj-rows]^T ----
  aload(XB0, Xf + bJ, lo);
  aload(XB1, Xf + bJ + 4096, lo);
  aload(Aa, Zf + aI, lo);
#pragma unroll
  for (int q = 0; q < 16; ++q) { m0[q] = -3.0e38f; m1[q] = -3.0e38f; }

  aload(Ab, Zf + HS + aI, lo);      mstep(Aa, XB0, XB1, m0, m1);
  aload(Aa, Zf + 2 * HS + aI, lo);  mstep(Ab, XB0, XB1, m0, m1);
  aload(Ab, Zf + 3 * HS + aI, lo);  mstep(Aa, XB0, XB1, m0, m1);
                                    mstep(Ab, XB0, XB1, m0, m1);

  // park phase-I result transposed in LDS: Tb[x][y] = maxI[y][x]
#pragma unroll
  for (int q = 0; q < 16; ++q) {
    int r = R0 + (q & 3) + 8 * (q >> 2) + 4 * fh;
    Tb[tidx(C0 + fr, r)]      = m0[q];
    Tb[tidx(C0 + 32 + fr, r)] = m1[q];
  }
  __syncthreads();

  const float beta = betap[0];
  const bool bp = (beta != 1.0f);

  if (diag) {
#pragma unroll
    for (int q = 0; q < 16; ++q) {
      int r = R0 + (q & 3) + 8 * (q >> 2) + 4 * fh;
      {
        int c = C0 + fr;
        float v = 0.25f * (m0[q] + Tb[tidx(r, c)]) + 0.5f;
        if (bp) v = powf(v, beta);
        out[(size_t)(bi * BT + r) * N_NODES + (size_t)(bi * BT + c)] = v;
      }
      {
        int c = C0 + 32 + fr;
        float v = 0.25f * (m1[q] + Tb[tidx(r, c)]) + 0.5f;
        if (bp) v = powf(v, beta);
        out[(size_t)(bi * BT + r) * N_NODES + (size_t)(bi * BT + c)] = v;
      }
    }
    return;
  }

  // ---- phase J: m = max_h Z[h][bj-rows] . Xe[bi-rows]^T  (reuse m0/m1) ----
  aload(XB0, Xf + bI, lo);
  aload(XB1, Xf + bI + 4096, lo);
  aload(Aa, Zf + aJ, lo);
#pragma unroll
  for (int q = 0; q < 16; ++q) { m0[q] = -3.0e38f; m1[q] = -3.0e38f; }

  aload(Ab, Zf + HS + aJ, lo);      mstep(Aa, XB0, XB1, m0, m1);
  aload(Aa, Zf + 2 * HS + aJ, lo);  mstep(Ab, XB0, XB1, m0, m1);
  aload(Ab, Zf + 3 * HS + aJ, lo);  mstep(Aa, XB0, XB1, m0, m1);
                                    mstep(Ab, XB0, XB1, m0, m1);

  // lower tile: v[r^][c^] = 0.25*(maxJ[r^][c^] + maxI[c^][r^]) + 0.5
  float vv[2][16];
#pragma unroll
  for (int q = 0; q < 16; ++q) {
    int r = R0 + (q & 3) + 8 * (q >> 2) + 4 * fh;
    {
      int c = C0 + fr;
      float v = 0.25f * (m0[q] + Tb[tidx(r, c)]) + 0.5f;
      if (bp) v = powf(v, beta);
      out[(size_t)(bj * BT + r) * N_NODES + (size_t)(bi * BT + c)] = v;
      vv[0][q] = v;
    }
    {
      int c = C0 + 32 + fr;
      float v = 0.25f * (m1[q] + Tb[tidx(r, c)]) + 0.5f;
      if (bp) v = powf(v, beta);
      out[(size_t)(bj * BT + r) * N_NODES + (size_t)(bi * BT + c)] = v;
      vv[1][q] = v;
    }
  }

  __syncthreads();   // all Tb(maxI) reads done
  // store v transposed, then mirror coalesced to the upper tile
#pragma unroll
  for (int q = 0; q < 16; ++q) {
    int r = R0 + (q & 3) + 8 * (q >> 2) + 4 * fh;
    Tb[tidx(C0 + fr, r)]      = vv[0][q];
    Tb[tidx(C0 + 32 + fr, r)] = vv[1][q];
  }
  __syncthreads();
#pragma unroll
  for (int it = 0; it < 32; ++it) {
    int row = it * 4 + (t >> 7);
    int col = t & 127;
    out[(size_t)(bi * BT + row) * N_NODES + (size_t)(bj * BT + col)] =
        Tb[tidx(row, col)];
  }
}

extern "C" void kernel_launch(void* const* d_in, const int* in_sizes, int n_in,
                              void* d_out, int out_size, void* d_ws, size_t ws_size,
                              hipStream_t stream) {
  const float* X = (const float*)d_in[0];
  const float* W = (const float*)d_in[1];
  const float* Z = (const float*)d_in[2];
  const float* beta = (const float*)d_in[3];
  float* out = (float*)d_out;
  char* ws = (char*)d_ws;

  unsigned short* Xf = (unsigned short*)ws;                // 2 MiB frag-linear bf16
  unsigned short* Zf = (unsigned short*)(ws + (2u << 20)); // 8 MiB frag-linear bf16

  hipLaunchKernelGGL(xw_kernel, dim3(N_NODES / 32), dim3(512), 0, stream, X, W, Xf);
  hipLaunchKernelGGL(znorm_kernel, dim3(N_HEADS * N_NODES / 4), dim3(256), 0, stream, Z, Zf);
  hipLaunchKernelGGL(affinity_kernel, dim3(NPAIR), dim3(512), 0, stream, Xf, Zf, beta, out);
}